// Round 2
// baseline (298.738 us; speedup 1.0000x reference)
//
#include <hip/hip_runtime.h>
#include <math.h>

#define BG   16
#define NPG  400
#define NN   (BG*NPG)      // 6400 nodes
#define KNN  20
#define NH   8
#define HD   16
#define EM   128
#define NL   3
#define NEGS 0.2f
#define BNEPS 1e-5f
#define MAXDEG 192
#define ROWW 16            // u32 words per adjacency row (512 bits >= 400)
#define NSLOT 7            // ceil(400/64) candidates per lane
#define BNB  32            // blocks in BN stage-1

// ---------------- kNN: one wave per node, register top-20 -------------------
__global__ __launch_bounds__(512) void knn_kernel(const float* __restrict__ pos,
                                                  unsigned* __restrict__ rowmask) {
    int wave = threadIdx.x >> 6, lane = threadIdx.x & 63;
    int i = blockIdx.x * 8 + wave;      // global node
    int g = i / NPG, li = i - g * NPG;  // graph, local index
    const float* pg = pos + (size_t)g * NPG * 2;
    float xi = pg[li * 2], yi = pg[li * 2 + 1];

    // per-lane candidate distances: j = lane + 64*s
    float dl[NSLOT];
    #pragma unroll
    for (int s = 0; s < NSLOT; ++s) {
        int j = lane + (s << 6);
        if (j < NPG && j != li) {
            float dx = __fsub_rn(xi, pg[j * 2]);
            float dy = __fsub_rn(yi, pg[j * 2 + 1]);
            dl[s] = __fadd_rn(__fmul_rn(dx, dx), __fmul_rn(dy, dy));  // exact np rounding
        } else {
            dl[s] = INFINITY;
        }
    }

    int winj = -1;  // lane r (r<20) will hold the r-th selected neighbor
    #pragma unroll 1
    for (int r = 0; r < KNN; ++r) {
        // local argmin over NSLOT regs (static indices; strict < => lowest j wins ties)
        float bv = dl[0]; int bs = 0;
        #pragma unroll
        for (int s = 1; s < NSLOT; ++s)
            if (dl[s] < bv) { bv = dl[s]; bs = s; }
        int bj = lane + (bs << 6);
        // wave butterfly argmin on (value, index), lower index wins ties
        #pragma unroll
        for (int off = 32; off > 0; off >>= 1) {
            float ov = __shfl_xor(bv, off);
            int   oj = __shfl_xor(bj, off);
            if (ov < bv || (ov == bv && oj < bj)) { bv = ov; bj = oj; }
        }
        // owner lane retires the winner (static unrolled indexing)
        if ((bj & 63) == lane) {
            int s = bj >> 6;
            #pragma unroll
            for (int q = 0; q < NSLOT; ++q) if (q == s) dl[q] = INFINITY;
        }
        if (lane == r) winj = bj;
    }

    // adjacency bits: forward + reverse (lanes 0..19), self loop (lane 20)
    if (lane < KNN) {
        atomicOr(&rowmask[(size_t)i * ROWW + (winj >> 5)], 1u << (winj & 31));
        atomicOr(&rowmask[((size_t)g * NPG + winj) * ROWW + (li >> 5)], 1u << (li & 31));
    } else if (lane == KNN) {
        atomicOr(&rowmask[(size_t)i * ROWW + (li >> 5)], 1u << (li & 31));
    }
}

// ---------------- bitmask -> compact neighbor lists -------------------------
__global__ void nbr_kernel(const unsigned* __restrict__ rowmask,
                           int* __restrict__ nbr, int* __restrict__ cnt) {
    int i = blockIdx.x * blockDim.x + threadIdx.x;
    if (i >= NN) return;
    int base = (i / NPG) * NPG;
    int c = 0;
    for (int w = 0; w < 13; ++w) {
        unsigned m = rowmask[(size_t)i * ROWW + w];
        while (m) {
            int b = __ffs(m) - 1;
            m &= m - 1;
            int j = w * 32 + b;
            if (j < NPG && c < MAXDEG) nbr[(size_t)i * MAXDEG + c++] = base + j;
        }
    }
    cnt[i] = c;
}

// ---------------- input projection ------------------------------------------
__global__ void proj_kernel(const float* __restrict__ x, const float* __restrict__ w,
                            const float* __restrict__ b, float* __restrict__ h) {
    int idx = blockIdx.x * blockDim.x + threadIdx.x;  // n*128 + c
    if (idx >= NN * EM) return;
    int n = idx >> 7, c = idx & 127;
    float acc = x[n * 3 + 0] * w[0 * EM + c] + x[n * 3 + 1] * w[1 * EM + c]
              + x[n * 3 + 2] * w[2 * EM + c] + b[c];
    h[idx] = acc;
}

// ---------------- hh = h @ W (6400x128 @ 128x128) ---------------------------
__global__ __launch_bounds__(256) void matmul_kernel(const float* __restrict__ h,
                                                     const float* __restrict__ w,
                                                     float* __restrict__ out) {
    __shared__ float hs[16][EM];
    int row0 = blockIdx.x * 16;
    int t = threadIdx.x;
    for (int idx = t; idx < 16 * EM; idx += 256)
        hs[idx >> 7][idx & 127] = h[(size_t)row0 * EM + idx];
    __syncthreads();
    int c = t & 127, half = t >> 7;
    float acc[8] = {0, 0, 0, 0, 0, 0, 0, 0};
    for (int k = 0; k < EM; ++k) {
        float wv = w[k * EM + c];
        #pragma unroll
        for (int rr = 0; rr < 8; ++rr) acc[rr] += hs[half * 8 + rr][k] * wv;
    }
    for (int rr = 0; rr < 8; ++rr)
        out[(size_t)(row0 + half * 8 + rr) * EM + c] = acc[rr];
}

// ---------------- per-(node,head) attention scores --------------------------
__global__ void score_kernel(const float* __restrict__ hh, const float* __restrict__ asrc,
                             const float* __restrict__ adst, float* __restrict__ ssrc,
                             float* __restrict__ sdst) {
    int idx = blockIdx.x * blockDim.x + threadIdx.x;  // n*8 + head
    if (idx >= NN * NH) return;
    int n = idx >> 3, hd = idx & 7;
    const float* hp = hh + (size_t)n * EM + hd * HD;
    float s1 = 0.f, s2 = 0.f;
    #pragma unroll
    for (int d = 0; d < HD; ++d) { s1 += hp[d] * asrc[hd * HD + d]; s2 += hp[d] * adst[hd * HD + d]; }
    ssrc[idx] = s1;
    sdst[idx] = s2;
}

// ---------------- sparse masked softmax + aggregate -------------------------
__global__ __launch_bounds__(128) void attn_kernel(const float* __restrict__ hh,
                                                   const int* __restrict__ nbr,
                                                   const int* __restrict__ cnt,
                                                   const float* __restrict__ ssrc,
                                                   const float* __restrict__ sdst,
                                                   const float* __restrict__ bias,
                                                   float* __restrict__ out) {
    int i = blockIdx.x;
    int t = threadIdx.x;  // channel = head*16 + d
    __shared__ float sc[MAXDEG][NH];
    __shared__ int   nb[MAXDEG];
    __shared__ float inv[NH];
    int c = cnt[i];
    for (int j = t; j < c; j += 128) nb[j] = nbr[(size_t)i * MAXDEG + j];
    __syncthreads();
    for (int idx = t; idx < c * NH; idx += 128) {
        int jj = idx >> 3, hd = idx & 7;
        float v = sdst[i * NH + hd] + ssrc[nb[jj] * NH + hd];
        sc[jj][hd] = v >= 0.f ? v : NEGS * v;  // leaky_relu
    }
    __syncthreads();
    if (t < NH) {
        float mx = -INFINITY;
        for (int jj = 0; jj < c; ++jj) mx = fmaxf(mx, sc[jj][t]);
        float s = 0.f;
        for (int jj = 0; jj < c; ++jj) { float e = expf(sc[jj][t] - mx); sc[jj][t] = e; s += e; }
        inv[t] = 1.f / s;
    }
    __syncthreads();
    int hd = t >> 4;
    float acc = 0.f;
    for (int jj = 0; jj < c; ++jj) acc += sc[jj][hd] * hh[(size_t)nb[jj] * EM + t];
    out[(size_t)i * EM + t] = acc * inv[hd] + bias[t];
}

// ---------------- BatchNorm stats, 2-stage coalesced ------------------------
__global__ __launch_bounds__(256) void bnstat1_kernel(const float* __restrict__ x,
                                                      float* __restrict__ part) {
    int blk = blockIdx.x, t = threadIdx.x;
    int c = t & 127, half = t >> 7;
    const int rows = NN / BNB;  // 200
    float s1 = 0.f, s2 = 0.f;
    for (int k = half; k < rows; k += 2) {
        float v = x[(size_t)(blk * rows + k) * EM + c];
        s1 += v; s2 += v * v;
    }
    __shared__ float l1[256], l2[256];
    l1[t] = s1; l2[t] = s2;
    __syncthreads();
    if (half == 0) {
        part[blk * EM + c] = l1[c] + l1[c + 128];
        part[(BNB + blk) * EM + c] = l2[c] + l2[c + 128];
    }
}

__global__ __launch_bounds__(128) void bnstat2_kernel(const float* __restrict__ part,
                                                      float* __restrict__ mean,
                                                      float* __restrict__ rstd) {
    int c = threadIdx.x;
    float s1 = 0.f, s2 = 0.f;
    for (int b = 0; b < BNB; ++b) { s1 += part[b * EM + c]; s2 += part[(BNB + b) * EM + c]; }
    float m = s1 / NN;
    float v = s2 / NN - m * m;
    mean[c] = m;
    rstd[c] = rsqrtf(v + BNEPS);
}

// ---------------- BN apply + ELU + residual (in-place into h) ---------------
__global__ void bnapply_kernel(const float* __restrict__ gout, const float* __restrict__ mean,
                               const float* __restrict__ rstd, const float* __restrict__ gamma,
                               const float* __restrict__ beta, float* __restrict__ h) {
    int idx = blockIdx.x * blockDim.x + threadIdx.x;
    if (idx >= NN * EM) return;
    int c = idx & 127;
    float v = (gout[idx] - mean[c]) * rstd[c] * gamma[c] + beta[c];
    v = v > 0.f ? v : expm1f(v);  // elu
    h[idx] = v + h[idx];          // residual
}

// ---------------- outputs ----------------------------------------------------
__global__ void copy_kernel(const float* __restrict__ h, float* __restrict__ out) {
    int idx = blockIdx.x * blockDim.x + threadIdx.x;
    if (idx < NN * EM) out[idx] = h[idx];
}

__global__ __launch_bounds__(256) void gmean_kernel(const float* __restrict__ h,
                                                    float* __restrict__ out) {
    int b = blockIdx.x, t = threadIdx.x;
    int c = t & 127, half = t >> 7;
    float s = 0.f;
    for (int n = half; n < NPG; n += 2) s += h[((size_t)b * NPG + n) * EM + c];
    __shared__ float l[256];
    l[t] = s;
    __syncthreads();
    if (half == 0) out[NN * EM + b * EM + c] = (l[c] + l[c + 128]) / 400.0f;
}

extern "C" void kernel_launch(void* const* d_in, const int* in_sizes, int n_in,
                              void* d_out, int out_size, void* d_ws, size_t ws_size,
                              hipStream_t stream) {
    const float* x      = (const float*)d_in[0];
    const float* pos    = (const float*)d_in[1];
    // d_in[2] = batch (int32), unused: graphs are contiguous blocks of 400
    const float* proj_w = (const float*)d_in[3];
    const float* proj_b = (const float*)d_in[4];
    const float* lin_w  = (const float*)d_in[5];
    const float* asrc   = (const float*)d_in[6];
    const float* adst   = (const float*)d_in[7];
    const float* gbias  = (const float*)d_in[8];
    const float* gamma  = (const float*)d_in[9];
    const float* beta   = (const float*)d_in[10];
    float* out = (float*)d_out;

    // workspace carve-up (16B aligned chunks)
    char* p = (char*)d_ws;
    auto take = [&](size_t bytes) { char* q = p; p += (bytes + 15) & ~(size_t)15; return q; };
    unsigned* rowmask = (unsigned*)take((size_t)NN * ROWW * 4);
    int*      nbr     = (int*)take((size_t)NN * MAXDEG * 4);
    int*      cnt     = (int*)take((size_t)NN * 4);
    float*    h       = (float*)take((size_t)NN * EM * 4);
    float*    hh      = (float*)take((size_t)NN * EM * 4);
    float*    gout    = (float*)take((size_t)NN * EM * 4);
    float*    ssrc    = (float*)take((size_t)NN * NH * 4);
    float*    sdst    = (float*)take((size_t)NN * NH * 4);
    float*    part    = (float*)take((size_t)2 * BNB * EM * 4);
    float*    mean    = (float*)take(EM * 4);
    float*    rstd    = (float*)take(EM * 4);

    hipMemsetAsync(rowmask, 0, (size_t)NN * ROWW * 4, stream);
    knn_kernel<<<NN / 8, 512, 0, stream>>>(pos, rowmask);
    nbr_kernel<<<(NN + 255) / 256, 256, 0, stream>>>(rowmask, nbr, cnt);
    proj_kernel<<<(NN * EM + 255) / 256, 256, 0, stream>>>(x, proj_w, proj_b, h);

    for (int l = 0; l < NL; ++l) {
        matmul_kernel<<<NN / 16, 256, 0, stream>>>(h, lin_w + (size_t)l * EM * EM, hh);
        score_kernel<<<(NN * NH + 255) / 256, 256, 0, stream>>>(hh, asrc + (size_t)l * EM,
                                                                adst + (size_t)l * EM, ssrc, sdst);
        attn_kernel<<<NN, 128, 0, stream>>>(hh, nbr, cnt, ssrc, sdst,
                                            gbias + (size_t)l * EM, gout);
        bnstat1_kernel<<<BNB, 256, 0, stream>>>(gout, part);
        bnstat2_kernel<<<1, 128, 0, stream>>>(part, mean, rstd);
        bnapply_kernel<<<(NN * EM + 255) / 256, 256, 0, stream>>>(gout, mean, rstd,
                                                                  gamma + (size_t)l * EM,
                                                                  beta + (size_t)l * EM, h);
    }

    copy_kernel<<<(NN * EM + 255) / 256, 256, 0, stream>>>(h, out);
    gmean_kernel<<<BG, 256, 0, stream>>>(h, out);
}

// Round 3
// 240.001 us; speedup vs baseline: 1.2447x; 1.2447x over previous
//
#include <hip/hip_runtime.h>
#include <math.h>

#define BG   16
#define NPG  400
#define NN   (BG*NPG)      // 6400 nodes
#define KNN  20
#define NH   8
#define HD   16
#define EM   128
#define NL   3
#define NEGS 0.2f
#define BNEPS 1e-5f
#define MAXDEG 192
#define ROWW 16            // u32 words per adjacency row (512 bits >= 400)
#define NSLOT 7            // ceil(400/64) candidates per lane
#define SNB  32            // blocks in BN stat kernel

// ---------------- kNN: one wave per node, register top-20 -------------------
__global__ __launch_bounds__(512) void knn_kernel(const float* __restrict__ pos,
                                                  unsigned* __restrict__ rowmask) {
    int wave = threadIdx.x >> 6, lane = threadIdx.x & 63;
    int i = blockIdx.x * 8 + wave;      // global node
    int g = i / NPG, li = i - g * NPG;  // graph, local index
    const float* pg = pos + (size_t)g * NPG * 2;
    float xi = pg[li * 2], yi = pg[li * 2 + 1];

    float dl[NSLOT];
    #pragma unroll
    for (int s = 0; s < NSLOT; ++s) {
        int j = lane + (s << 6);
        if (j < NPG && j != li) {
            float dx = __fsub_rn(xi, pg[j * 2]);
            float dy = __fsub_rn(yi, pg[j * 2 + 1]);
            dl[s] = __fadd_rn(__fmul_rn(dx, dx), __fmul_rn(dy, dy));  // exact np rounding
        } else {
            dl[s] = INFINITY;
        }
    }

    int winj = -1;  // lane r (r<20) holds the r-th selected neighbor
    #pragma unroll 1
    for (int r = 0; r < KNN; ++r) {
        float bv = dl[0]; int bs = 0;
        #pragma unroll
        for (int s = 1; s < NSLOT; ++s)
            if (dl[s] < bv) { bv = dl[s]; bs = s; }
        int bj = lane + (bs << 6);
        #pragma unroll
        for (int off = 32; off > 0; off >>= 1) {
            float ov = __shfl_xor(bv, off);
            int   oj = __shfl_xor(bj, off);
            if (ov < bv || (ov == bv && oj < bj)) { bv = ov; bj = oj; }
        }
        if ((bj & 63) == lane) {
            int s = bj >> 6;
            #pragma unroll
            for (int q = 0; q < NSLOT; ++q) if (q == s) dl[q] = INFINITY;
        }
        if (lane == r) winj = bj;
    }

    if (lane < KNN) {
        atomicOr(&rowmask[(size_t)i * ROWW + (winj >> 5)], 1u << (winj & 31));
        atomicOr(&rowmask[((size_t)g * NPG + winj) * ROWW + (li >> 5)], 1u << (li & 31));
    } else if (lane == KNN) {
        atomicOr(&rowmask[(size_t)i * ROWW + (li >> 5)], 1u << (li & 31));
    }
}

// ---------------- bitmask -> compact neighbor lists -------------------------
__global__ void nbr_kernel(const unsigned* __restrict__ rowmask,
                           int* __restrict__ nbr, int* __restrict__ cnt) {
    int i = blockIdx.x * blockDim.x + threadIdx.x;
    if (i >= NN) return;
    int base = (i / NPG) * NPG;
    int c = 0;
    for (int w = 0; w < 13; ++w) {
        unsigned m = rowmask[(size_t)i * ROWW + w];
        while (m) {
            int b = __ffs(m) - 1;
            m &= m - 1;
            int j = w * 32 + b;
            if (j < NPG && c < MAXDEG) nbr[(size_t)i * MAXDEG + c++] = base + j;
        }
    }
    cnt[i] = c;
}

// ---------------- input projection ------------------------------------------
__global__ void proj_kernel(const float* __restrict__ x, const float* __restrict__ w,
                            const float* __restrict__ b, float* __restrict__ h) {
    int idx = blockIdx.x * blockDim.x + threadIdx.x;  // n*128 + c
    if (idx >= NN * EM) return;
    int n = idx >> 7, c = idx & 127;
    float acc = x[n * 3 + 0] * w[0 * EM + c] + x[n * 3 + 1] * w[1 * EM + c]
              + x[n * 3 + 2] * w[2 * EM + c] + b[c];
    h[idx] = acc;
}

// ---- fused: [BN+ELU+residual of prev layer] + hh = h@W + score projections -
// gout==nullptr for layer 0 (h comes straight from proj).
// Block 0 also zeroes `statz` (this layer's BN stat accumulator).
__global__ __launch_bounds__(256) void mmscore_kernel(
        float* __restrict__ h, const float* __restrict__ gout,
        const float* __restrict__ stat, const float* __restrict__ gamma,
        const float* __restrict__ beta, const float* __restrict__ w,
        const float* __restrict__ asrc, const float* __restrict__ adst,
        float* __restrict__ hh, float* __restrict__ ssrc, float* __restrict__ sdst,
        float* __restrict__ statz) {
    __shared__ float hs[16][EM];
    int row0 = blockIdx.x * 16;
    int t = threadIdx.x;
    if (blockIdx.x == 0) statz[t] = 0.f;

    // stage h rows (optionally finishing previous layer's BN+ELU+residual)
    for (int idx = t; idx < 16 * EM; idx += 256) {
        int r = idx >> 7, c = idx & 127;
        size_t gi = (size_t)(row0 + r) * EM + c;
        float v;
        if (gout) {
            float m  = stat[c] * (1.f / NN);
            float vr = stat[EM + c] * (1.f / NN) - m * m;
            float bnv = (gout[gi] - m) * rsqrtf(vr + BNEPS) * gamma[c] + beta[c];
            bnv = bnv > 0.f ? bnv : expm1f(bnv);       // elu
            v = bnv + h[gi];                           // residual
            h[gi] = v;
        } else {
            v = h[gi];
        }
        hs[r][c] = v;
    }
    __syncthreads();

    int cc = t & 127, half = t >> 7;
    float acc[8] = {0, 0, 0, 0, 0, 0, 0, 0};
    const float* wp = w + cc;
    for (int k = 0; k < EM; k += 4) {
        float w0 = wp[(k + 0) * EM], w1 = wp[(k + 1) * EM];
        float w2 = wp[(k + 2) * EM], w3 = wp[(k + 3) * EM];
        #pragma unroll
        for (int rr = 0; rr < 8; ++rr) {
            const float4 hv = *(const float4*)&hs[half * 8 + rr][k];  // wave-broadcast
            acc[rr] = fmaf(hv.x, w0, fmaf(hv.y, w1, fmaf(hv.z, w2, fmaf(hv.w, w3, acc[rr]))));
        }
    }
    #pragma unroll
    for (int rr = 0; rr < 8; ++rr)
        hh[(size_t)(row0 + half * 8 + rr) * EM + cc] = acc[rr];
    __syncthreads();
    // reuse hs to stage hh for the score dots
    #pragma unroll
    for (int rr = 0; rr < 8; ++rr) hs[half * 8 + rr][cc] = acc[rr];
    __syncthreads();
    if (t < 16 * NH) {
        int row = t >> 3, hd = t & 7;
        const float* ap = asrc + hd * HD;
        const float* dp = adst + hd * HD;
        float s1 = 0.f, s2 = 0.f;
        #pragma unroll
        for (int d = 0; d < HD; ++d) {
            float v = hs[row][hd * HD + d];
            s1 += v * ap[d]; s2 += v * dp[d];
        }
        ssrc[(size_t)(row0 + row) * NH + hd] = s1;
        sdst[(size_t)(row0 + row) * NH + hd] = s2;
    }
}

// ---------------- sparse masked softmax + aggregate -------------------------
__global__ __launch_bounds__(128) void attn_kernel(const float* __restrict__ hh,
                                                   const int* __restrict__ nbr,
                                                   const int* __restrict__ cnt,
                                                   const float* __restrict__ ssrc,
                                                   const float* __restrict__ sdst,
                                                   const float* __restrict__ bias,
                                                   float* __restrict__ out) {
    int i = blockIdx.x;
    int t = threadIdx.x;
    __shared__ float sc[MAXDEG][NH];
    __shared__ int   nb[MAXDEG];
    __shared__ float red[16][NH];
    __shared__ float hm[NH];
    __shared__ float inv[NH];
    int c = cnt[i];
    for (int j = t; j < c; j += 128) nb[j] = nbr[(size_t)i * MAXDEG + j];
    __syncthreads();
    for (int idx = t; idx < c * NH; idx += 128) {
        int jj = idx >> 3, hd = idx & 7;
        float v = sdst[i * NH + hd] + ssrc[nb[jj] * NH + hd];
        sc[jj][hd] = v >= 0.f ? v : NEGS * v;  // leaky_relu
    }
    __syncthreads();
    int hd = t & 7, st = t >> 3;  // 16 stripes x 8 heads
    float mx = -INFINITY;
    for (int jj = st; jj < c; jj += 16) mx = fmaxf(mx, sc[jj][hd]);
    red[st][hd] = mx;
    __syncthreads();
    if (t < NH) {
        float m = red[0][t];
        for (int s = 1; s < 16; ++s) m = fmaxf(m, red[s][t]);
        hm[t] = m;
    }
    __syncthreads();
    float m = hm[hd];
    float ps = 0.f;
    for (int jj = st; jj < c; jj += 16) {
        float e = expf(sc[jj][hd] - m);
        sc[jj][hd] = e;
        ps += e;
    }
    red[st][hd] = ps;
    __syncthreads();
    if (t < NH) {
        float s = 0.f;
        for (int q = 0; q < 16; ++q) s += red[q][t];
        inv[t] = 1.f / s;
    }
    __syncthreads();
    int hdc = t >> 4;
    float acc = 0.f;
    for (int jj = 0; jj < c; ++jj) acc += sc[jj][hdc] * hh[(size_t)nb[jj] * EM + t];
    out[(size_t)i * EM + t] = acc * inv[hdc] + bias[t];
}

// ---------------- BN stats: 32 blocks, LDS partials, atomic combine ---------
__global__ __launch_bounds__(256) void bnstat_kernel(const float* __restrict__ x,
                                                     float* __restrict__ stat) {
    int blk = blockIdx.x, t = threadIdx.x;
    int c = t & 127, half = t >> 7;
    const int rows = NN / SNB;  // 200
    float s1 = 0.f, s2 = 0.f;
    for (int k = half; k < rows; k += 2) {
        float v = x[(size_t)(blk * rows + k) * EM + c];
        s1 += v; s2 += v * v;
    }
    __shared__ float l1[256], l2[256];
    l1[t] = s1; l2[t] = s2;
    __syncthreads();
    if (half == 0) {
        atomicAdd(&stat[c], l1[c] + l1[c + 128]);
        atomicAdd(&stat[EM + c], l2[c] + l2[c + 128]);
    }
}

// ---- final: BN+ELU+residual of layer 2 -> node out + graph-mean atomics ----
__global__ __launch_bounds__(256) void finish_kernel(const float* __restrict__ gout,
                                                     const float* __restrict__ stat,
                                                     const float* __restrict__ gamma,
                                                     const float* __restrict__ beta,
                                                     const float* __restrict__ h,
                                                     float* __restrict__ out) {
    int b = blockIdx.x;          // 16 graphs x 8 chunks of 50 rows
    int g = b >> 3, ch = b & 7;
    int t = threadIdx.x, c = t & 127, half = t >> 7;
    float m  = stat[c] * (1.f / NN);
    float vr = stat[EM + c] * (1.f / NN) - m * m;
    float rs = rsqrtf(vr + BNEPS);
    float ga = gamma[c], be = beta[c];
    int r0 = g * NPG + ch * 50;
    float s = 0.f;
    for (int k = half; k < 50; k += 2) {
        size_t gi = (size_t)(r0 + k) * EM + c;
        float v = (gout[gi] - m) * rs * ga + be;
        v = v > 0.f ? v : expm1f(v);
        v += h[gi];
        out[gi] = v;
        s += v;
    }
    __shared__ float l1[256];
    l1[t] = s;
    __syncthreads();
    if (half == 0)
        atomicAdd(&out[(size_t)NN * EM + g * EM + c], (l1[c] + l1[c + 128]) * (1.f / NPG));
}

extern "C" void kernel_launch(void* const* d_in, const int* in_sizes, int n_in,
                              void* d_out, int out_size, void* d_ws, size_t ws_size,
                              hipStream_t stream) {
    const float* x      = (const float*)d_in[0];
    const float* pos    = (const float*)d_in[1];
    // d_in[2] = batch (int32), unused: graphs are contiguous blocks of 400
    const float* proj_w = (const float*)d_in[3];
    const float* proj_b = (const float*)d_in[4];
    const float* lin_w  = (const float*)d_in[5];
    const float* asrc   = (const float*)d_in[6];
    const float* adst   = (const float*)d_in[7];
    const float* gbias  = (const float*)d_in[8];
    const float* gamma  = (const float*)d_in[9];
    const float* beta   = (const float*)d_in[10];
    float* out = (float*)d_out;

    char* p = (char*)d_ws;
    auto take = [&](size_t bytes) { char* q = p; p += (bytes + 15) & ~(size_t)15; return q; };
    unsigned* rowmask = (unsigned*)take((size_t)NN * ROWW * 4);
    int*      nbr     = (int*)take((size_t)NN * MAXDEG * 4);
    int*      cnt     = (int*)take((size_t)NN * 4);
    float*    h       = (float*)take((size_t)NN * EM * 4);
    float*    hh      = (float*)take((size_t)NN * EM * 4);
    float*    gout    = (float*)take((size_t)NN * EM * 4);
    float*    ssrc    = (float*)take((size_t)NN * NH * 4);
    float*    sdst    = (float*)take((size_t)NN * NH * 4);
    float*    statA   = (float*)take((size_t)2 * EM * 4);
    float*    statB   = (float*)take((size_t)2 * EM * 4);
    float*    statv[2] = {statA, statB};

    hipMemsetAsync(rowmask, 0, (size_t)NN * ROWW * 4, stream);
    hipMemsetAsync(out + (size_t)NN * EM, 0, (size_t)BG * EM * 4, stream);
    knn_kernel<<<NN / 8, 512, 0, stream>>>(pos, rowmask);
    nbr_kernel<<<(NN + 255) / 256, 256, 0, stream>>>(rowmask, nbr, cnt);
    proj_kernel<<<(NN * EM + 255) / 256, 256, 0, stream>>>(x, proj_w, proj_b, h);

    for (int l = 0; l < NL; ++l) {
        float* statz = statv[l & 1];          // this layer's accumulator (zeroed in mmscore)
        const float* statp = statv[(l + 1) & 1];  // previous layer's stats
        mmscore_kernel<<<NN / 16, 256, 0, stream>>>(
            h, l ? gout : nullptr, statp,
            gamma + (size_t)(l - 1) * EM, beta + (size_t)(l - 1) * EM,
            lin_w + (size_t)l * EM * EM, asrc + (size_t)l * EM, adst + (size_t)l * EM,
            hh, ssrc, sdst, statz);
        attn_kernel<<<NN, 128, 0, stream>>>(hh, nbr, cnt, ssrc, sdst,
                                            gbias + (size_t)l * EM, gout);
        bnstat_kernel<<<SNB, 256, 0, stream>>>(gout, statz);
    }

    finish_kernel<<<BG * 8, 256, 0, stream>>>(gout, statv[2 & 1],
                                              gamma + (size_t)2 * EM, beta + (size_t)2 * EM,
                                              h, out);
}

// Round 4
// 231.530 us; speedup vs baseline: 1.2903x; 1.0366x over previous
//
#include <hip/hip_runtime.h>
#include <math.h>

#define BG   16
#define NPG  400
#define NN   (BG*NPG)      // 6400 nodes
#define KNN  20
#define NH   8
#define HD   16
#define EM   128
#define NL   3
#define NEGS 0.2f
#define BNEPS 1e-5f
#define MAXDEG 192
#define ROWW 16            // u32 words per adjacency row (512 bits >= 400)
#define NSLOT 7            // ceil(400/64) candidates per lane
#define SNB  32            // blocks in BN stat kernel

// ---------------- kNN: one wave per node, register top-20 -------------------
__global__ __launch_bounds__(512) void knn_kernel(const float* __restrict__ pos,
                                                  unsigned* __restrict__ rowmask) {
    int wave = threadIdx.x >> 6, lane = threadIdx.x & 63;
    int i = blockIdx.x * 8 + wave;      // global node
    int g = i / NPG, li = i - g * NPG;  // graph, local index
    const float* pg = pos + (size_t)g * NPG * 2;
    float xi = pg[li * 2], yi = pg[li * 2 + 1];

    float dl[NSLOT];
    #pragma unroll
    for (int s = 0; s < NSLOT; ++s) {
        int j = lane + (s << 6);
        if (j < NPG && j != li) {
            float dx = __fsub_rn(xi, pg[j * 2]);
            float dy = __fsub_rn(yi, pg[j * 2 + 1]);
            dl[s] = __fadd_rn(__fmul_rn(dx, dx), __fmul_rn(dy, dy));  // exact np rounding
        } else {
            dl[s] = INFINITY;
        }
    }

    int winj = -1;  // lane r (r<20) holds the r-th selected neighbor
    #pragma unroll 1
    for (int r = 0; r < KNN; ++r) {
        float bv = dl[0]; int bs = 0;
        #pragma unroll
        for (int s = 1; s < NSLOT; ++s)
            if (dl[s] < bv) { bv = dl[s]; bs = s; }
        int bj = lane + (bs << 6);
        #pragma unroll
        for (int off = 32; off > 0; off >>= 1) {
            float ov = __shfl_xor(bv, off);
            int   oj = __shfl_xor(bj, off);
            if (ov < bv || (ov == bv && oj < bj)) { bv = ov; bj = oj; }
        }
        if ((bj & 63) == lane) {
            int s = bj >> 6;
            #pragma unroll
            for (int q = 0; q < NSLOT; ++q) if (q == s) dl[q] = INFINITY;
        }
        if (lane == r) winj = bj;
    }

    if (lane < KNN) {
        atomicOr(&rowmask[(size_t)i * ROWW + (winj >> 5)], 1u << (winj & 31));
        atomicOr(&rowmask[((size_t)g * NPG + winj) * ROWW + (li >> 5)], 1u << (li & 31));
    } else if (lane == KNN) {
        atomicOr(&rowmask[(size_t)i * ROWW + (li >> 5)], 1u << (li & 31));
    }
}

// -------- bitmask -> compact neighbor lists (+ zero graph-mean out tail) ----
__global__ void nbr_kernel(const unsigned* __restrict__ rowmask,
                           int* __restrict__ nbr, int* __restrict__ cnt,
                           float* __restrict__ out) {
    if (blockIdx.x < 8)   // zero the graph-mean region: 16*128 = 2048 floats
        out[(size_t)NN * EM + blockIdx.x * 256 + threadIdx.x] = 0.f;
    int i = blockIdx.x * blockDim.x + threadIdx.x;
    if (i >= NN) return;
    int base = (i / NPG) * NPG;
    int c = 0;
    for (int w = 0; w < 13; ++w) {
        unsigned m = rowmask[(size_t)i * ROWW + w];
        while (m) {
            int b = __ffs(m) - 1;
            m &= m - 1;
            int j = w * 32 + b;
            if (j < NPG && c < MAXDEG) nbr[(size_t)i * MAXDEG + c++] = base + j;
        }
    }
    cnt[i] = c;
}

// ---- fused: [proj (l=0) | BN+ELU+residual (l>0)] + hh = h@W + score dots ---
__global__ __launch_bounds__(256) void mmscore_kernel(
        float* __restrict__ h, const float* __restrict__ gout,
        const float* __restrict__ stat, const float* __restrict__ gamma,
        const float* __restrict__ beta, const float* __restrict__ x,
        const float* __restrict__ pw, const float* __restrict__ pb,
        const float* __restrict__ w,
        const float* __restrict__ asrc, const float* __restrict__ adst,
        float* __restrict__ hh, float* __restrict__ ssrc, float* __restrict__ sdst,
        float* __restrict__ statz) {
    __shared__ float hs[16][EM];
    int row0 = blockIdx.x * 16;
    int t = threadIdx.x;
    if (blockIdx.x == 0) statz[t] = 0.f;   // zero this layer's BN accumulator

    for (int idx = t; idx < 16 * EM; idx += 256) {
        int r = idx >> 7, c = idx & 127;
        size_t gi = (size_t)(row0 + r) * EM + c;
        float v;
        if (gout) {
            float m  = stat[c] * (1.f / NN);
            float vr = stat[EM + c] * (1.f / NN) - m * m;
            float bnv = (gout[gi] - m) * rsqrtf(vr + BNEPS) * gamma[c] + beta[c];
            bnv = bnv > 0.f ? bnv : expm1f(bnv);       // elu
            v = bnv + h[gi];                           // residual
        } else {
            int n = row0 + r;                          // input projection
            v = x[n * 3 + 0] * pw[0 * EM + c] + x[n * 3 + 1] * pw[1 * EM + c]
              + x[n * 3 + 2] * pw[2 * EM + c] + pb[c];
        }
        h[gi] = v;
        hs[r][c] = v;
    }
    __syncthreads();

    int cc = t & 127, half = t >> 7;
    float acc[8] = {0, 0, 0, 0, 0, 0, 0, 0};
    const float* wp = w + cc;
    for (int k = 0; k < EM; k += 4) {
        float w0 = wp[(k + 0) * EM], w1 = wp[(k + 1) * EM];
        float w2 = wp[(k + 2) * EM], w3 = wp[(k + 3) * EM];
        #pragma unroll
        for (int rr = 0; rr < 8; ++rr) {
            const float4 hv = *(const float4*)&hs[half * 8 + rr][k];
            acc[rr] = fmaf(hv.x, w0, fmaf(hv.y, w1, fmaf(hv.z, w2, fmaf(hv.w, w3, acc[rr]))));
        }
    }
    #pragma unroll
    for (int rr = 0; rr < 8; ++rr)
        hh[(size_t)(row0 + half * 8 + rr) * EM + cc] = acc[rr];
    __syncthreads();
    #pragma unroll
    for (int rr = 0; rr < 8; ++rr) hs[half * 8 + rr][cc] = acc[rr];
    __syncthreads();
    if (t < 16 * NH) {
        int row = t >> 3, hd = t & 7;
        const float* ap = asrc + hd * HD;
        const float* dp = adst + hd * HD;
        float s1 = 0.f, s2 = 0.f;
        #pragma unroll
        for (int d = 0; d < HD; ++d) {
            float v = hs[row][hd * HD + d];
            s1 += v * ap[d]; s2 += v * dp[d];
        }
        ssrc[(size_t)(row0 + row) * NH + hd] = s1;
        sdst[(size_t)(row0 + row) * NH + hd] = s2;
    }
}

// ------------ attention: ONE WAVE per node, shuffle softmax -----------------
__global__ __launch_bounds__(64) void attn_kernel(const float* __restrict__ hh,
                                                  const int* __restrict__ nbr,
                                                  const int* __restrict__ cnt,
                                                  const float* __restrict__ ssrc,
                                                  const float* __restrict__ sdst,
                                                  const float* __restrict__ bias,
                                                  float* __restrict__ out) {
    int i = blockIdx.x;
    int lane = threadIdx.x;
    __shared__ float sc[MAXDEG * NH];   // sc[jj*8 + head]
    __shared__ int   nb[MAXDEG];
    int c = cnt[i];
    for (int j = lane; j < c; j += 64) nb[j] = nbr[(size_t)i * MAXDEG + j];
    __syncthreads();
    for (int idx = lane; idx < c * NH; idx += 64) {
        int jj = idx >> 3, hd = idx & 7;
        float v = sdst[i * NH + hd] + ssrc[nb[jj] * NH + hd];
        sc[idx] = v >= 0.f ? v : NEGS * v;   // leaky_relu
    }
    __syncthreads();
    // per-head softmax: 8 lanes per head (hd = lane&7, sub = lane>>3)
    int hd = lane & 7, sub = lane >> 3;
    float mx = -INFINITY;
    for (int jj = sub; jj < c; jj += 8) mx = fmaxf(mx, sc[jj * 8 + hd]);
    #pragma unroll
    for (int off = 8; off < 64; off <<= 1) mx = fmaxf(mx, __shfl_xor(mx, off));
    float s = 0.f;
    for (int jj = sub; jj < c; jj += 8) {
        float e = expf(sc[jj * 8 + hd] - mx);
        sc[jj * 8 + hd] = e;
        s += e;
    }
    #pragma unroll
    for (int off = 8; off < 64; off <<= 1) s += __shfl_xor(s, off);
    float inv = 1.f / s;                 // lane k (k<8) holds inv for head k
    __syncthreads();
    // PV: lane owns channels lane and lane+64 (heads h0 and h0+4)
    int h0 = lane >> 4;
    float invh0 = __shfl(inv, h0);
    float invh1 = __shfl(inv, h0 + 4);
    float acc0 = 0.f, acc1 = 0.f;
    for (int jj = 0; jj < c; ++jj) {
        const float* hp = hh + (size_t)nb[jj] * EM;
        acc0 += sc[jj * 8 + h0] * hp[lane];
        acc1 += sc[jj * 8 + h0 + 4] * hp[lane + 64];
    }
    out[(size_t)i * EM + lane]      = acc0 * invh0 + bias[lane];
    out[(size_t)i * EM + lane + 64] = acc1 * invh1 + bias[lane + 64];
}

// ---------------- BN stats: 32 blocks, LDS partials, atomic combine ---------
__global__ __launch_bounds__(256) void bnstat_kernel(const float* __restrict__ x,
                                                     float* __restrict__ stat) {
    int blk = blockIdx.x, t = threadIdx.x;
    int c = t & 127, half = t >> 7;
    const int rows = NN / SNB;  // 200
    float s1 = 0.f, s2 = 0.f;
    for (int k = half; k < rows; k += 2) {
        float v = x[(size_t)(blk * rows + k) * EM + c];
        s1 += v; s2 += v * v;
    }
    __shared__ float l1[256], l2[256];
    l1[t] = s1; l2[t] = s2;
    __syncthreads();
    if (half == 0) {
        atomicAdd(&stat[c], l1[c] + l1[c + 128]);
        atomicAdd(&stat[EM + c], l2[c] + l2[c + 128]);
    }
}

// ---- final: BN+ELU+residual of layer 2 -> node out + graph-mean atomics ----
__global__ __launch_bounds__(256) void finish_kernel(const float* __restrict__ gout,
                                                     const float* __restrict__ stat,
                                                     const float* __restrict__ gamma,
                                                     const float* __restrict__ beta,
                                                     const float* __restrict__ h,
                                                     float* __restrict__ out) {
    int b = blockIdx.x;          // 16 graphs x 8 chunks of 50 rows
    int g = b >> 3, ch = b & 7;
    int t = threadIdx.x, c = t & 127, half = t >> 7;
    float m  = stat[c] * (1.f / NN);
    float vr = stat[EM + c] * (1.f / NN) - m * m;
    float rs = rsqrtf(vr + BNEPS);
    float ga = gamma[c], be = beta[c];
    int r0 = g * NPG + ch * 50;
    float s = 0.f;
    for (int k = half; k < 50; k += 2) {
        size_t gi = (size_t)(r0 + k) * EM + c;
        float v = (gout[gi] - m) * rs * ga + be;
        v = v > 0.f ? v : expm1f(v);
        v += h[gi];
        out[gi] = v;
        s += v;
    }
    __shared__ float l1[256];
    l1[t] = s;
    __syncthreads();
    if (half == 0)
        atomicAdd(&out[(size_t)NN * EM + g * EM + c], (l1[c] + l1[c + 128]) * (1.f / NPG));
}

extern "C" void kernel_launch(void* const* d_in, const int* in_sizes, int n_in,
                              void* d_out, int out_size, void* d_ws, size_t ws_size,
                              hipStream_t stream) {
    const float* x      = (const float*)d_in[0];
    const float* pos    = (const float*)d_in[1];
    // d_in[2] = batch (int32), unused: graphs are contiguous blocks of 400
    const float* proj_w = (const float*)d_in[3];
    const float* proj_b = (const float*)d_in[4];
    const float* lin_w  = (const float*)d_in[5];
    const float* asrc   = (const float*)d_in[6];
    const float* adst   = (const float*)d_in[7];
    const float* gbias  = (const float*)d_in[8];
    const float* gamma  = (const float*)d_in[9];
    const float* beta   = (const float*)d_in[10];
    float* out = (float*)d_out;

    char* p = (char*)d_ws;
    auto take = [&](size_t bytes) { char* q = p; p += (bytes + 15) & ~(size_t)15; return q; };
    unsigned* rowmask = (unsigned*)take((size_t)NN * ROWW * 4);
    int*      nbr     = (int*)take((size_t)NN * MAXDEG * 4);
    int*      cnt     = (int*)take((size_t)NN * 4);
    float*    h       = (float*)take((size_t)NN * EM * 4);
    float*    hh      = (float*)take((size_t)NN * EM * 4);
    float*    gout    = (float*)take((size_t)NN * EM * 4);
    float*    ssrc    = (float*)take((size_t)NN * NH * 4);
    float*    sdst    = (float*)take((size_t)NN * NH * 4);
    float*    statA   = (float*)take((size_t)2 * EM * 4);
    float*    statB   = (float*)take((size_t)2 * EM * 4);
    float*    statv[2] = {statA, statB};

    hipMemsetAsync(rowmask, 0, (size_t)NN * ROWW * 4, stream);
    knn_kernel<<<NN / 8, 512, 0, stream>>>(pos, rowmask);
    nbr_kernel<<<(NN + 255) / 256, 256, 0, stream>>>(rowmask, nbr, cnt, out);

    for (int l = 0; l < NL; ++l) {
        float* statz = statv[l & 1];
        const float* statp = statv[(l + 1) & 1];
        int lp = l ? l - 1 : 0;
        mmscore_kernel<<<NN / 16, 256, 0, stream>>>(
            h, l ? gout : nullptr, statp,
            gamma + (size_t)lp * EM, beta + (size_t)lp * EM,
            x, proj_w, proj_b,
            lin_w + (size_t)l * EM * EM, asrc + (size_t)l * EM, adst + (size_t)l * EM,
            hh, ssrc, sdst, statz);
        attn_kernel<<<NN, 64, 0, stream>>>(hh, nbr, cnt, ssrc, sdst,
                                           gbias + (size_t)l * EM, gout);
        bnstat_kernel<<<SNB, 256, 0, stream>>>(gout, statz);
    }

    finish_kernel<<<BG * 8, 256, 0, stream>>>(gout, statv[2 & 1],
                                              gamma + (size_t)2 * EM, beta + (size_t)2 * EM,
                                              h, out);
}